// Round 8
// baseline (36.086 us; speedup 1.0000x reference)
//
#include <hip/hip_runtime.h>
#include <stdint.h>

// MosaicSDF: N=1024 points, G=512 grids, K=7 (343 nodes/grid).
// R8: single kernel, block (256 thr = 4 waves) per point.
//   Phase 1: each wave sweeps 128 grids (2 ballot rounds), ballot-scan
//     compacts active (rx,ry,rz,gwr)+gid into per-wave LDS segments.
//   Phase 2: 16-lane group per active pair. Row staged via ALIGNED uint4
//     loads of the covering 16B window (residual shift d0 folded into the
//     read base) -> 6 dwordx4 loads/lane instead of 43 scalar (4x fewer
//     TA addresses). Lane computes rows {sub,sub+16,sub+32} (7 nodes each,
//     mul-shift div-7 decode) + one node of row 48 for sub<7. 4-step
//     group reduce. Software-pipelined staging. No atomics, no workspace.

#define NPTS    1024
#define NGRIDS  512
#define TPB     256
#define NW      4
#define NGRP    16
#define ROWBLKS 88             // 16B blocks per staged row region (1408 B)
#define ROWBYTES 1372          // 343 floats
#define STEP    (1.0f / 6.0f)
#define FSQRT(x) __builtin_amdgcn_sqrtf(x)

__global__ __launch_bounds__(TPB, 4) void msdf_fused(
    const float* __restrict__ points,    // (N,3)
    const float* __restrict__ centers,   // (G,3)
    const float* __restrict__ scales,    // (G,)
    const float* __restrict__ vals,      // (G,343)
    float* __restrict__ out)             // (N,)
{
    __shared__ uint4  s_v[NGRP][ROWBLKS];     // 22528 B staged rows
    __shared__ float4 s_pair[NW][128];        // (rx,ry,rz,gwr) per active
    __shared__ unsigned short s_gid[NW][128];
    __shared__ int   s_c[NW];
    __shared__ float s_d[NW];
    __shared__ float s_a[NW];

    const int n    = blockIdx.x;
    const int t    = threadIdx.x;
    const int w    = t >> 6;
    const int lane = t & 63;
    const int grp  = t >> 4;             // 0..15: 16-lane group (pair slot)
    const int sub  = t & 15;

    const float px = points[n * 3 + 0];  // uniform -> scalar loads
    const float py = points[n * 3 + 1];
    const float pz = points[n * 3 + 2];

    // ---- Phase 1: activity sweep + ballot-scan compaction ----
    float dsum  = 0.0f;
    int   cbase = 0;
    #pragma unroll
    for (int r = 0; r < 2; ++r) {
        const int g = w * 128 + r * 64 + lane;
        const float invs = 1.0f / scales[g];
        const float rx = (px - centers[g * 3 + 0]) * invs;
        const float ry = (py - centers[g * 3 + 1]) * invs;
        const float rz = (pz - centers[g * 3 + 2]) * invs;
        const float gwr = 1.0f - FSQRT(rx * rx + ry * ry + rz * rz);
        const bool  act = (gwr > 0.0f);
        const unsigned long long m = __ballot(act);
        if (act) {
            const int pos = cbase + (int)__popcll(m & ((1ull << lane) - 1ull));
            s_pair[w][pos] = make_float4(rx, ry, rz, gwr);
            s_gid[w][pos]  = (unsigned short)g;
            dsum += gwr;
        }
        cbase += (int)__popcll(m);
    }
    #pragma unroll
    for (int off = 32; off >= 1; off >>= 1) dsum += __shfl_xor(dsum, off);
    if (lane == 0) { s_c[w] = cbase; s_d[w] = dsum; }
    __syncthreads();

    const int off1 = s_c[0];
    const int off2 = off1 + s_c[1];
    const int off3 = off2 + s_c[2];
    const int C    = off3 + s_c[3];
    const float den = s_d[0] + s_d[1] + s_d[2] + s_d[3];

    // ---- Phase 2: 16-lane group per pair, aligned-x4 staging ----
    float acc = 0.0f;

    auto fetchPair = [&](int p, float4& pr, int& gid) {
        const int seg = (p >= off1) + (p >= off2) + (p >= off3);
        const int base = (seg == 0) ? 0 : (seg == 1) ? off1 : (seg == 2) ? off2 : off3;
        const int idx = p - base;
        pr  = s_pair[seg][idx];
        gid = (int)s_gid[seg][idx];
    };

    if (C > 0) {
        const int nch = (C + NGRP - 1) >> 4;
        uint4 rbuf[6];
        float4 pr;  int gid;

        auto loadRow = [&](int g) {
            const int rb    = g * ROWBYTES;
            const int A     = rb & ~15;
            const int d0    = rb & 15;
            const int lastb = (d0 + ROWBYTES - 1) >> 4;     // 85 or 86
            const uint4* __restrict__ src = (const uint4*)((const char*)vals + A);
            #pragma unroll
            for (int k = 0; k < 6; ++k) {
                const int b  = sub + 16 * k;
                const int bc = (b < lastb) ? b : lastb;
                rbuf[k] = src[bc];
            }
        };

        fetchPair((grp < C) ? grp : (C - 1), pr, gid);
        loadRow(gid);

        for (int c = 0; c < nch; ++c) {
            // Commit staged row (chunk c) to this group's LDS region.
            #pragma unroll
            for (int k = 0; k < 6; ++k) {
                const int b = sub + 16 * k;
                if (b < ROWBLKS) s_v[grp][b] = rbuf[k];
            }
            const float4 prc  = pr;
            const int    gidc = gid;
            const float  gw   = (c * NGRP + grp < C) ? prc.w : 0.0f;

            // Prefetch next chunk's row while computing this one.
            if (c + 1 < nch) {
                const int pn = (c + 1) * NGRP + grp;
                fetchPair((pn < C) ? pn : (C - 1), pr, gid);
                loadRow(gid);
            }

            // LDS writes visible to the whole (same-wave) group.
            asm volatile("s_waitcnt lgkmcnt(0)" ::: "memory");

            const int d0 = (gidc * ROWBYTES) & 15;
            const float* __restrict__ myrow =
                (const float*)(&s_v[grp][0]) + (d0 >> 2);

            float dz2[7];
            #pragma unroll
            for (int l = 0; l < 7; ++l) { const float d = prc.z - l * STEP; dz2[l] = d * d; }

            float ws = 0.0f, vs = 0.0f;
            #pragma unroll
            for (int rr = 0; rr < 3; ++rr) {
                const int rowid = sub + 16 * rr;             // 0..47
                const int i = (rowid * 9363) >> 16;          // rowid / 7
                const int j = rowid - i * 7;
                const float dxv = prc.x - (float)i * STEP;
                const float dyv = prc.y - (float)j * STEP;
                const float dxy = dxv * dxv + dyv * dyv;
                const float* __restrict__ vr = myrow + rowid * 7;
                #pragma unroll
                for (int l = 0; l < 7; ++l) {
                    const float d2 = dxy + dz2[l];
                    const float wt = (d2 <= 1.0f) ? FSQRT(d2) : 0.0f;
                    ws += wt;
                    vs  = fmaf(wt, vr[l], vs);
                }
            }
            if (sub < 7) {                                   // row 48: node (6,6,sub)
                const float dxv = prc.x - 1.0f;
                const float dyv = prc.y - 1.0f;
                const float dzv = prc.z - (float)sub * STEP;
                const float d2  = dxv * dxv + dyv * dyv + dzv * dzv;
                const float wt  = (d2 <= 1.0f) ? FSQRT(d2) : 0.0f;
                ws += wt;
                vs  = fmaf(wt, myrow[336 + sub], vs);
            }
            #pragma unroll
            for (int o = 8; o >= 1; o >>= 1) {
                ws += __shfl_xor(ws, o);
                vs += __shfl_xor(vs, o);
            }
            const float interp = (ws > 0.0f) ? (vs / ws) : 0.0f;
            if (sub == 0) acc += interp * gw;
        }
    }

    // Block reduction of per-group partials (sub==0 lanes hold them).
    #pragma unroll
    for (int o = 32; o >= 1; o >>= 1) acc += __shfl_xor(acc, o);
    if (lane == 0) s_a[w] = acc;
    __syncthreads();
    if (t == 0) {
        const float ns = s_a[0] + s_a[1] + s_a[2] + s_a[3];
        out[n] = (den > 0.0f) ? (ns / den) : 0.0f;
    }
}

extern "C" void kernel_launch(void* const* d_in, const int* in_sizes, int n_in,
                              void* d_out, int out_size, void* d_ws, size_t ws_size,
                              hipStream_t stream) {
    const float* points  = (const float*)d_in[0];   // (1024,3)
    const float* centers = (const float*)d_in[1];   // (512,3)
    const float* scales  = (const float*)d_in[2];   // (512,)
    const float* vals    = (const float*)d_in[3];   // (512,7,7,7)
    float* out = (float*)d_out;                     // (1024,)

    msdf_fused<<<NPTS, TPB, 0, stream>>>(points, centers, scales, vals, out);
}

// Round 9
// 34.411 us; speedup vs baseline: 1.0487x; 1.0487x over previous
//
#include <hip/hip_runtime.h>
#include <stdint.h>

// MosaicSDF: N=1024 points, G=512 grids, K=7 (343 nodes/grid).
// R9 = R7 skeleton (proven 17us, absmax 0) + aligned-uint4 staging:
//   Phase 1: 2 waves sweep 512 grids (4 ballot rounds), centers/scales
//     pre-staged in LDS (aliased with row buffer); ballot-scan compacts
//     active (rx,ry,rz,gwr)+gid into LDS; wave-reduce den.
//   Phase 2: 8-lane group per active pair. Row staged via 11 ALIGNED
//     dwordx4 loads of the covering 16B window (residual shift d0 folded
//     into the LDS read base) instead of 43 scalar loads -> ~4x fewer TA
//     addresses. LDS row pitch 91 blocks (364 dwords = 12 mod 32) to
//     de-alias the 8 groups' banks. Software-pipelined (prefetch chunk
//     c+1 during compute of c). NO asm memory clobber (R8's scratch-spill
//     poison) - compiler's own lgkmcnt ordering is correct (R7, absmax 0).
//   No atomics, no workspace, one dispatch.

#define NPTS     1024
#define NGRIDS   512
#define ROWBYTES 1372          // 343 floats
#define ROWPITCH 91            // uint4 blocks per staged row (1456 B)
#define STEP     (1.0f / 6.0f)
#define FSQRT(x) __builtin_amdgcn_sqrtf(x)

__global__ __launch_bounds__(128) void msdf_fused(
    const float* __restrict__ points,    // (N,3)
    const float* __restrict__ centers,   // (G,3)
    const float* __restrict__ scales,    // (G,)
    const float* __restrict__ vals,      // (G,343)
    float* __restrict__ out)             // (N,)
{
    __shared__ uint4  s_v[16][ROWPITCH];     // 23,296 B staged rows
    __shared__ float4 s_pair[2][256];        // (rx,ry,rz,gwr) per active, per half
    __shared__ unsigned short s_gid[2][256];
    __shared__ int   s_c[2];
    __shared__ float s_d[2];
    __shared__ float s_a[2];

    const int n    = blockIdx.x;
    const int t    = threadIdx.x;
    const int h    = t >> 6;             // wave half: grids [h*256, h*256+256)
    const int lane = t & 63;
    const int grp  = lane >> 3;          // 8-lane group id (pair slot)
    const int sub  = lane & 7;

    // Stage centers+scales into LDS (aliased with s_v; phase-1 only).
    float* s_cen = (float*)&s_v[0][0];   // 1536 floats
    float* s_scl = s_cen + 1536;         // 512 floats (8 KB total, fits)
    {
        const float4* c4 = (const float4*)centers;        // 384 float4
        #pragma unroll
        for (int i = 0; i < 3; ++i) ((float4*)s_cen)[t + i * 128] = c4[t + i * 128];
        ((float4*)s_scl)[t] = ((const float4*)scales)[t]; // 128 float4
    }
    const float px = points[n * 3 + 0];  // uniform -> scalar loads
    const float py = points[n * 3 + 1];
    const float pz = points[n * 3 + 2];
    __syncthreads();

    // ---- Phase 1: activity sweep + ballot-scan compaction ----
    float dsum  = 0.0f;
    int   cbase = 0;
    #pragma unroll
    for (int r = 0; r < 4; ++r) {
        const int g = h * 256 + r * 64 + lane;
        const float invs = 1.0f / s_scl[g];
        const float rx = (px - s_cen[g * 3 + 0]) * invs;
        const float ry = (py - s_cen[g * 3 + 1]) * invs;
        const float rz = (pz - s_cen[g * 3 + 2]) * invs;
        const float gwr = 1.0f - FSQRT(rx * rx + ry * ry + rz * rz);
        const bool  act = (gwr > 0.0f);
        const unsigned long long m = __ballot(act);
        if (act) {
            const int pos = cbase + (int)__popcll(m & ((1ull << lane) - 1ull));
            s_pair[h][pos] = make_float4(rx, ry, rz, gwr);
            s_gid[h][pos]  = (unsigned short)g;
            dsum += gwr;
        }
        cbase += (int)__popcll(m);
    }
    #pragma unroll
    for (int off = 32; off >= 1; off >>= 1) dsum += __shfl_xor(dsum, off);
    if (lane == 0) { s_c[h] = cbase; s_d[h] = dsum; }
    __syncthreads();                     // also: s_cen/s_scl alias reads done

    // ---- Phase 2: 8-lane group per pair, aligned-x4 staging, pipelined ----
    const int   c0  = s_c[0];
    const int   C   = c0 + s_c[1];
    const float den = s_d[0] + s_d[1];

    const int base = h * 8 + grp;        // this group's pair-slot stride base
    const int nch  = (C > h * 8) ? ((C - h * 8 + 15) >> 4) : 0;
    uint4* __restrict__ myblk = &s_v[h * 8 + grp][0];   // group's LDS region

    struct PairInfo { float4 pr; int gid; };
    auto fetchPair = [&](int p) -> PairInfo {
        const int pc = (p < C) ? p : (C - 1);
        const int ia = (pc < c0) ? 0 : 1;
        const int jp = (pc < c0) ? pc : pc - c0;
        PairInfo r;
        r.pr  = s_pair[ia][jp];
        r.gid = (int)s_gid[ia][jp];
        return r;
    };

    float acc = 0.0f;
    if (nch > 0) {
        uint4 rbuf[11];

        auto loadRow = [&](int g) {
            const int rb    = g * ROWBYTES;
            const int A     = rb & ~15;
            const int d0    = rb & 15;
            const int lastb = (d0 + ROWBYTES - 1) >> 4;   // 85 or 86
            const uint4* __restrict__ src = (const uint4*)((const char*)vals + A);
            #pragma unroll
            for (int k = 0; k < 11; ++k) {
                const int b  = sub + 8 * k;               // 0..87
                const int bc = (b < lastb) ? b : lastb;
                rbuf[k] = src[bc];
            }
        };

        PairInfo cur = fetchPair(base);
        loadRow(cur.gid);

        for (int c = 0; c < nch; ++c) {
            // Commit staged row (chunk c) to this group's LDS region.
            #pragma unroll
            for (int k = 0; k < 11; ++k) myblk[sub + 8 * k] = rbuf[k];

            const float4 prc  = cur.pr;
            const int    gidc = cur.gid;
            const float  gw   = (16 * c + base < C) ? prc.w : 0.0f;

            // Prefetch next chunk's row while computing this one.
            if (c + 1 < nch) {
                cur = fetchPair(16 * (c + 1) + base);
                loadRow(cur.gid);
            }

            // Read base: fold the row's 16B-misalignment into the offset.
            const int d0 = (gidc * ROWBYTES) & 15;
            const float* __restrict__ myrow = (const float*)myblk + (d0 >> 2);

            float dy2[7], dz2[7];
            #pragma unroll
            for (int j = 0; j < 7; ++j) { const float d = prc.y - j * STEP; dy2[j] = d * d; }
            #pragma unroll
            for (int l = 0; l < 7; ++l) { const float d = prc.z - l * STEP; dz2[l] = d * d; }

            const int   slab = (sub < 7) ? sub : 6;
            const float dxv  = prc.x - slab * STEP;
            const float dx2  = (sub < 7) ? dxv * dxv : 4.0f;   // sub==7 -> wt 0
            const float* __restrict__ vrow = myrow + slab * 49;

            float ws = 0.0f, vs = 0.0f;
            #pragma unroll
            for (int j = 0; j < 7; ++j) {
                const float dxy = dx2 + dy2[j];
                #pragma unroll
                for (int l = 0; l < 7; ++l) {
                    const float d2 = dxy + dz2[l];
                    const float wt = (d2 <= 1.0f) ? FSQRT(d2) : 0.0f;
                    ws += wt;
                    vs  = fmaf(wt, vrow[j * 7 + l], vs);
                }
            }
            #pragma unroll
            for (int off = 4; off >= 1; off >>= 1) {
                ws += __shfl_xor(ws, off);
                vs += __shfl_xor(vs, off);
            }
            const float interp = (ws > 0.0f) ? (vs / ws) : 0.0f;
            if (sub == 0) acc += interp * gw;
        }
    }

    // Sum the 8 group contributions (sub==0 lanes hold partials).
    #pragma unroll
    for (int off = 32; off >= 1; off >>= 1) acc += __shfl_xor(acc, off);
    if (lane == 0) s_a[h] = acc;
    __syncthreads();
    if (t == 0)
        out[n] = (den > 0.0f) ? ((s_a[0] + s_a[1]) / den) : 0.0f;
}

extern "C" void kernel_launch(void* const* d_in, const int* in_sizes, int n_in,
                              void* d_out, int out_size, void* d_ws, size_t ws_size,
                              hipStream_t stream) {
    const float* points  = (const float*)d_in[0];   // (1024,3)
    const float* centers = (const float*)d_in[1];   // (512,3)
    const float* scales  = (const float*)d_in[2];   // (512,)
    const float* vals    = (const float*)d_in[3];   // (512,7,7,7)
    float* out = (float*)d_out;                     // (1024,)

    msdf_fused<<<NPTS, 128, 0, stream>>>(points, centers, scales, vals, out);
}